// Round 3
// baseline (1979.480 us; speedup 1.0000x reference)
//
#include <hip/hip_runtime.h>
#include <math.h>

#define NN 50000
#define NE 800000

typedef short bf16x8 __attribute__((ext_vector_type(8)));
typedef float f32x4 __attribute__((ext_vector_type(4)));

__device__ inline ushort f2bf(float f) {
    union { float f; uint u; } v; v.f = f;
    uint r = v.u + 0x7FFFu + ((v.u >> 16) & 1u);
    return (ushort)(r >> 16);
}
__device__ inline float bf2f(ushort h) {
    union { uint u; float f; } v; v.u = ((uint)h) << 16;
    return v.f;
}

// ---------------- CSR build ----------------

__global__ void count_edges_k(const int* __restrict__ edst, int* __restrict__ counts, int e) {
    int i = blockIdx.x * blockDim.x + threadIdx.x;
    if (i < e) atomicAdd(&counts[edst[i]], 1);
}

// hierarchical exclusive scan: scan1 (per-block excl + block sums), scan2 (scan sums), scan3 (add offsets)
__global__ __launch_bounds__(1024) void scan1_k(const int* __restrict__ counts,
                                                int* __restrict__ row_start,
                                                int* __restrict__ bsum, int n) {
    __shared__ int sd[1024];
    int i = blockIdx.x * 1024 + threadIdx.x;
    int v = (i < n) ? counts[i] : 0;
    sd[threadIdx.x] = v;
    __syncthreads();
    for (int off = 1; off < 1024; off <<= 1) {
        int t = (threadIdx.x >= off) ? sd[threadIdx.x - off] : 0;
        __syncthreads();
        sd[threadIdx.x] += t;
        __syncthreads();
    }
    if (i < n) row_start[i] = sd[threadIdx.x] - v;
    if (threadIdx.x == 1023) bsum[blockIdx.x] = sd[1023];
}

__global__ void scan2_k(int* __restrict__ bsum, int nb) {
    int lane = threadIdx.x;  // blockDim = 64, nb <= 64
    int v = (lane < nb) ? bsum[lane] : 0;
    int orig = v;
    for (int off = 1; off < 64; off <<= 1) {
        int t = __shfl_up(v, off);
        if (lane >= off) v += t;
    }
    if (lane < nb) bsum[lane] = v - orig;
}

__global__ void scan3_k(const int* __restrict__ counts, const int* __restrict__ bsum,
                        int* __restrict__ row_start, int* __restrict__ cursor,
                        float* __restrict__ inv_deg, int n, int e) {
    int i = blockIdx.x * blockDim.x + threadIdx.x;
    if (i < n) {
        int rs = row_start[i] + bsum[i >> 10];
        row_start[i] = rs;
        cursor[i] = rs;
        inv_deg[i] = 1.0f / fmaxf((float)counts[i], 1.0f);
        if (i == 0) row_start[n] = e;
    }
}

__global__ void fill_csr_k(const int* __restrict__ esrc, const int* __restrict__ edst,
                           int* __restrict__ cursor, int* __restrict__ csr_src, int e) {
    int i = blockIdx.x * blockDim.x + threadIdx.x;
    if (i < e) {
        int pos = atomicAdd(&cursor[edst[i]], 1);
        csr_src[pos] = esrc[i];
    }
}

// ---------------- weight prep: Wt[c][k] = bf16(c < M ? W1[k][c] : W2[k][c-M]) ----------------

__global__ void prep_w_k(const float* __restrict__ W1, const float* __restrict__ W2,
                         ushort* __restrict__ Wt, int K, int M) {
    int i = blockIdx.x * blockDim.x + threadIdx.x;
    int tot = 2 * M * K;
    if (i >= tot) return;
    int c = i / K, k = i - c * K;
    float v = (c < M) ? W1[(size_t)k * M + c] : W2[(size_t)k * M + (c - M)];
    Wt[i] = f2bf(v);
}

// ---------------- MFMA GEMM: C[n, 2M] = A[n,K] @ Wt^T ; cols<M -> V, cols>=M -> R (both bf16) ---

template<bool A_FP32>
__global__ __launch_bounds__(256) void gemm_mfma_k(const void* __restrict__ Av, int K,
                                                   const ushort* __restrict__ Wt,
                                                   ushort* __restrict__ V,
                                                   ushort* __restrict__ Rr,
                                                   int M, int n) {
    __shared__ __align__(16) ushort As[64 * 40];
    __shared__ __align__(16) ushort Bs[128 * 40];
    int tid = threadIdx.x;
    int row0 = blockIdx.x * 64;
    int col0 = blockIdx.y * 128;
    int lane = tid & 63, wid = tid >> 6;
    int wm = wid & 1, wn = wid >> 1;
    int lrow = lane & 15, lko = (lane >> 4) * 8;

    f32x4 acc[2][4];
    #pragma unroll
    for (int i = 0; i < 2; ++i)
        #pragma unroll
        for (int j = 0; j < 4; ++j)
            acc[i][j] = (f32x4){0.f, 0.f, 0.f, 0.f};

    for (int kc = 0; kc < K; kc += 32) {
        __syncthreads();
        if constexpr (A_FP32) {
            const float* A = (const float*)Av;
            #pragma unroll
            for (int l = tid; l < 512; l += 256) {
                int r = l >> 3, s = l & 7;
                int rg = row0 + r;
                float4 a = (rg < n) ? *(const float4*)(A + (size_t)rg * K + kc + s * 4)
                                    : make_float4(0.f, 0.f, 0.f, 0.f);
                ushort* dst = &As[r * 40 + s * 4];
                dst[0] = f2bf(a.x); dst[1] = f2bf(a.y); dst[2] = f2bf(a.z); dst[3] = f2bf(a.w);
            }
        } else {
            const ushort* A = (const ushort*)Av;
            int r = tid >> 2, s = tid & 3;
            int rg = row0 + r;
            uint4 a = (rg < n) ? *(const uint4*)(A + (size_t)rg * K + kc + s * 8)
                               : make_uint4(0u, 0u, 0u, 0u);
            *(uint4*)(&As[r * 40 + s * 8]) = a;
        }
        #pragma unroll
        for (int l = tid; l < 512; l += 256) {
            int r = l >> 2, s = l & 3;
            int cg = col0 + r;
            *(uint4*)(&Bs[r * 40 + s * 8]) = *(const uint4*)(Wt + (size_t)cg * K + kc + s * 8);
        }
        __syncthreads();

        bf16x8 af[2], bfr[4];
        #pragma unroll
        for (int i = 0; i < 2; ++i)
            af[i] = *(const bf16x8*)(&As[(wm * 32 + i * 16 + lrow) * 40 + lko]);
        #pragma unroll
        for (int j = 0; j < 4; ++j)
            bfr[j] = *(const bf16x8*)(&Bs[(wn * 64 + j * 16 + lrow) * 40 + lko]);
        #pragma unroll
        for (int i = 0; i < 2; ++i)
            #pragma unroll
            for (int j = 0; j < 4; ++j)
                acc[i][j] = __builtin_amdgcn_mfma_f32_16x16x32_bf16(af[i], bfr[j], acc[i][j], 0, 0, 0);
    }

    #pragma unroll
    for (int i = 0; i < 2; ++i) {
        int rbase = row0 + wm * 32 + i * 16 + (lane >> 4) * 4;
        #pragma unroll
        for (int j = 0; j < 4; ++j) {
            int cg = col0 + wn * 64 + j * 16 + lrow;
            #pragma unroll
            for (int q = 0; q < 4; ++q) {
                int rg = rbase + q;
                if (rg < n) {
                    ushort hv = f2bf(acc[i][j][q]);
                    if (cg < M) V[(size_t)rg * M + cg] = hv;
                    else        Rr[(size_t)rg * M + (cg - M)] = hv;
                }
            }
        }
    }
}

// ---------------- col-tiled per-dst aggregation + combine ----------------
// out[dst,c] = act( mean_agg(V)[dst,c] + bias[c] + R[dst,c] ), all bf16 buffers.
// 32-column tiles; tile chosen by blockIdx.x & 7 so (round-robin dispatch) each
// XCD's L2 holds one 3.2MB column slice of V. Half-wave (32 lanes) per dst row.
// NT = M/32 tiles. ACT: 0=none 1=relu 2=sigmoid.

template<int NT, int ACT>
__global__ __launch_bounds__(256) void agg_tile_k(const ushort* __restrict__ V,
                                                  const ushort* __restrict__ Rr,
                                                  const float* __restrict__ bias,
                                                  const float* __restrict__ inv_deg,
                                                  const int* __restrict__ row_start,
                                                  const int* __restrict__ csr_src,
                                                  ushort* __restrict__ outb,
                                                  int ld_out, int n) {
    constexpr int M = NT * 32;
    constexpr int REP = 8 / NT;          // dst-group replication per slot
    int bid = blockIdx.x;
    int slot = bid & 7;
    int tile = slot / REP;
    int sub  = slot % REP;
    int dstgrp = (bid >> 3) * REP + sub;
    int dst = dstgrp * 8 + (threadIdx.x >> 5);
    if (dst >= n) return;
    int c = tile * 32 + (threadIdx.x & 31);

    float acc = 0.f;
    int s = row_start[dst], e = row_start[dst + 1];
    for (int j = s; j < e; ++j) {
        int src = csr_src[j];
        acc += bf2f(V[(size_t)src * M + c]);
    }
    float v = acc * inv_deg[dst];
    if (bias) v += bias[c];
    if (Rr)   v += bf2f(Rr[(size_t)dst * M + c]);
    if constexpr (ACT == 1) v = fmaxf(v, 0.f);
    else if constexpr (ACT == 2) v = 1.f / (1.f + expf(-v));
    outb[(size_t)dst * ld_out + c] = f2bf(v);
}

// ---------------- heads + cross-entropy ----------------

template<int C>
__device__ inline float head_one(const float* __restrict__ ah, const float* __restrict__ hh,
                                 const float* __restrict__ Wl, const float* __restrict__ bl,
                                 const float* __restrict__ Wr, int label) {
    float z[C];
    #pragma unroll
    for (int c = 0; c < C; ++c) z[c] = bl[c];
    for (int d = 0; d < 64; ++d) {
        float a = ah[d], h = hh[d];
        #pragma unroll
        for (int c = 0; c < C; ++c)
            z[c] = fmaf(a, Wl[d * C + c], fmaf(h, Wr[d * C + c], z[c]));
    }
    float m = -1e30f;
    #pragma unroll
    for (int c = 0; c < C; ++c) { z[c] = 1.f / (1.f + expf(-z[c])); m = fmaxf(m, z[c]); }
    float ssum = 0.f, zl = 0.f;
    #pragma unroll
    for (int c = 0; c < C; ++c) { ssum += expf(z[c] - m); if (c == label) zl = z[c]; }
    return (logf(ssum) + m) - zl;
}

__global__ __launch_bounds__(256) void head_ce_k(const ushort* __restrict__ Ah,
                                                 const ushort* __restrict__ hk,
                                                 const float* __restrict__ Wl1, const float* __restrict__ b1, const float* __restrict__ Wr1,
                                                 const float* __restrict__ Wl2, const float* __restrict__ b2, const float* __restrict__ Wr2,
                                                 const float* __restrict__ Wl3, const float* __restrict__ b3, const float* __restrict__ Wr3,
                                                 const int* __restrict__ y,
                                                 float* __restrict__ loss_acc, int n) {
    int nidx = blockIdx.x * blockDim.x + threadIdx.x;
    float lsum = 0.f;
    if (nidx < n) {
        float ah[64], hh[64];
        const ushort* ap = Ah + (size_t)nidx * 64;
        const ushort* hp = hk + (size_t)nidx * 64;
        #pragma unroll
        for (int d = 0; d < 64; ++d) { ah[d] = bf2f(ap[d]); hh[d] = bf2f(hp[d]); }
        lsum += head_one<12>(ah, hh, Wl1, b1, Wr1, y[nidx * 3 + 0]);
        lsum += head_one<8 >(ah, hh, Wl2, b2, Wr2, y[nidx * 3 + 1]);
        lsum += head_one<5 >(ah, hh, Wl3, b3, Wr3, y[nidx * 3 + 2]);
    }
    for (int off = 32; off > 0; off >>= 1) lsum += __shfl_down(lsum, off);
    __shared__ float ssum[4];
    int wv = threadIdx.x >> 6, ln = threadIdx.x & 63;
    if (ln == 0) ssum[wv] = lsum;
    __syncthreads();
    if (threadIdx.x == 0) atomicAdd(loss_acc, ssum[0] + ssum[1] + ssum[2] + ssum[3]);
}

__global__ void finalize_k(const float* __restrict__ loss_acc, float* __restrict__ out, int n) {
    out[0] = loss_acc[0] * (1.0f / (float)n);
}

// ---------------- host ----------------

extern "C" void kernel_launch(void* const* d_in, const int* in_sizes, int n_in,
                              void* d_out, int out_size, void* d_ws, size_t ws_size,
                              hipStream_t stream) {
    const float* X    = (const float*)d_in[0];
    const int*   esrc = (const int*)d_in[1];
    const int*   edst = (const int*)d_in[2];
    const int*   y    = (const int*)d_in[3];
    const float* Wl_i[2] = {(const float*)d_in[4], (const float*)d_in[7]};
    const float* bl_i[2] = {(const float*)d_in[5], (const float*)d_in[8]};
    const float* Wr_i[2] = {(const float*)d_in[6], (const float*)d_in[9]};
    const float* Wl_m = (const float*)d_in[10], *bl_m = (const float*)d_in[11], *Wr_m = (const float*)d_in[12];
    const float* Wl_o = (const float*)d_in[13], *bl_o = (const float*)d_in[14], *Wr_o = (const float*)d_in[15];
    const float* Wl_t1 = (const float*)d_in[16], *bl_t1 = (const float*)d_in[17], *Wr_t1 = (const float*)d_in[18];
    const float* Wl_t2 = (const float*)d_in[19], *bl_t2 = (const float*)d_in[20], *Wr_t2 = (const float*)d_in[21];
    const float* Wl_t3 = (const float*)d_in[22], *bl_t3 = (const float*)d_in[23], *Wr_t3 = (const float*)d_in[24];

    const int N = NN, E = NE;
    char* p = (char*)d_ws;
    auto alloc = [&](size_t bytes) -> char* {
        char* r = p;
        p += (bytes + 255) & ~(size_t)255;
        return r;
    };
    int*    counts    = (int*)alloc((size_t)N * 4);
    int*    row_start = (int*)alloc((size_t)(N + 1) * 4);
    int*    cursor    = (int*)alloc((size_t)N * 4);
    int*    bsum      = (int*)alloc(64 * 4);
    int*    csr_src   = (int*)alloc((size_t)E * 4);
    float*  inv_deg   = (float*)alloc((size_t)N * 4);
    float*  loss_acc  = (float*)alloc(256);
    ushort* V    = (ushort*)alloc((size_t)N * 256 * 2);
    ushort* R    = (ushort*)alloc((size_t)N * 256 * 2);
    ushort* xk   = (ushort*)alloc((size_t)N * 256 * 2);
    ushort* hk   = (ushort*)alloc((size_t)N * 64 * 2);
    ushort* Ah   = (ushort*)alloc((size_t)N * 64 * 2);
    ushort* Wt_i0 = (ushort*)alloc((size_t)256 * 128 * 2);
    ushort* Wt_i1 = (ushort*)alloc((size_t)256 * 128 * 2);
    ushort* Wt_m  = (ushort*)alloc((size_t)512 * 256 * 2);
    ushort* Wt_o  = (ushort*)alloc((size_t)128 * 256 * 2);

    hipMemsetAsync(counts, 0, (size_t)N * 4, stream);
    hipMemsetAsync(loss_acc, 0, 4, stream);
    count_edges_k<<<(E + 255) / 256, 256, 0, stream>>>(edst, counts, E);
    const int NB = (N + 1023) / 1024;  // 49
    scan1_k<<<NB, 1024, 0, stream>>>(counts, row_start, bsum, N);
    scan2_k<<<1, 64, 0, stream>>>(bsum, NB);
    scan3_k<<<(N + 255) / 256, 256, 0, stream>>>(counts, bsum, row_start, cursor, inv_deg, N, E);
    fill_csr_k<<<(E + 255) / 256, 256, 0, stream>>>(esrc, edst, cursor, csr_src, E);

    prep_w_k<<<(2 * 128 * 128 + 255) / 256, 256, 0, stream>>>(Wl_i[0], Wr_i[0], Wt_i0, 128, 128);
    prep_w_k<<<(2 * 128 * 128 + 255) / 256, 256, 0, stream>>>(Wl_i[1], Wr_i[1], Wt_i1, 128, 128);
    prep_w_k<<<(2 * 256 * 256 + 255) / 256, 256, 0, stream>>>(Wl_m, Wr_m, Wt_m, 256, 256);
    prep_w_k<<<(2 * 256 * 64 + 255) / 256, 256, 0, stream>>>(Wl_o, Wr_o, Wt_o, 256, 64);

    const int RB = (N + 63) / 64;            // 782 GEMM row blocks
    const int GRP = (N + 7) / 8;             // 6250 dst groups of 8
    const ushort* Wt_i[2] = {Wt_i0, Wt_i1};

    for (int k = 0; k < 2; ++k) {
        for (int ch = 0; ch < 2; ++ch) {
            const float* Xc = X + (size_t)(k * 2 + ch) * N * 128;
            gemm_mfma_k<true><<<dim3(RB, 2), 256, 0, stream>>>(Xc, 128, Wt_i[ch], V, R, 128, N);
            // M=128: NT=4, REP=2
            agg_tile_k<4, 1><<<((GRP + 1) / 2) * 8, 256, 0, stream>>>(V, R, bl_i[ch], inv_deg, row_start, csr_src,
                                                                      xk + ch * 128, 256, N);
        }
        gemm_mfma_k<false><<<dim3(RB, 4), 256, 0, stream>>>(xk, 256, Wt_m, V, R, 256, N);
        // M=256: NT=8, REP=1
        agg_tile_k<8, 1><<<GRP * 8, 256, 0, stream>>>(V, R, bl_m, inv_deg, row_start, csr_src,
                                                      xk, 256, N);
        gemm_mfma_k<false><<<dim3(RB, 1), 256, 0, stream>>>(xk, 256, Wt_o, V, R, 64, N);
        // M=64: NT=2, REP=4
        agg_tile_k<2, 2><<<((GRP + 3) / 4) * 8, 256, 0, stream>>>(V, R, bl_o, inv_deg, row_start, csr_src,
                                                                  hk, 64, N);
        agg_tile_k<2, 0><<<((GRP + 3) / 4) * 8, 256, 0, stream>>>(hk, nullptr, nullptr, inv_deg, row_start, csr_src,
                                                                  Ah, 64, N);
        head_ce_k<<<(N + 255) / 256, 256, 0, stream>>>(Ah, hk,
            Wl_t1 + (size_t)k * 64 * 12, bl_t1 + (size_t)k * 12, Wr_t1 + (size_t)k * 64 * 12,
            Wl_t2 + (size_t)k * 64 * 8,  bl_t2 + (size_t)k * 8,  Wr_t2 + (size_t)k * 64 * 8,
            Wl_t3 + (size_t)k * 64 * 5,  bl_t3 + (size_t)k * 5,  Wr_t3 + (size_t)k * 64 * 5,
            y + (size_t)k * N * 3, loss_acc, N);
    }
    finalize_k<<<1, 1, 0, stream>>>(loss_acc, (float*)d_out, N);
}

// Round 4
// 974.341 us; speedup vs baseline: 2.0316x; 2.0316x over previous
//
#include <hip/hip_runtime.h>
#include <math.h>

#define NN 50000
#define NE 800000

typedef short bf16x8 __attribute__((ext_vector_type(8)));
typedef float f32x4 __attribute__((ext_vector_type(4)));

__device__ inline ushort f2bf(float f) {
    union { float f; uint u; } v; v.f = f;
    uint r = v.u + 0x7FFFu + ((v.u >> 16) & 1u);
    return (ushort)(r >> 16);
}
__device__ inline float bf2f(ushort h) {
    union { uint u; float f; } v; v.u = ((uint)h) << 16;
    return v.f;
}
// fp8 e4m3fn software codecs (branch-free, exponent-shift trick)
__device__ inline uchar f2fp8(float f) {
    float a = fminf(fabsf(f), 448.f);
    union { float f; uint u; } v; v.f = a * 7.52316384526264e-37f;  // *2^-120
    uint r = (v.u + 0x7FFFFu + ((v.u >> 20) & 1u)) >> 20;           // RNE to e4m3 magnitude
    if (r > 0x7Eu) r = 0x7Eu;                                        // never emit NaN code
    union { float f; uint u; } s; s.f = f;
    return (uchar)(r | ((s.u >> 31) << 7));
}
__device__ inline float fp8dec(uint b) {
    union { uint u; float f; } t; t.u = (b & 0x7Fu) << 20;
    union { float f; uint u; } o; o.f = t.f * 1.3292279957849159e36f;  // *2^120
    o.u |= (b & 0x80u) << 24;
    return o.f;
}

// ---------------- CSR build ----------------

__global__ void count_edges_k(const int* __restrict__ edst, int* __restrict__ counts, int e) {
    int i = blockIdx.x * blockDim.x + threadIdx.x;
    if (i < e) atomicAdd(&counts[edst[i]], 1);
}

__global__ __launch_bounds__(1024) void scan1_k(const int* __restrict__ counts,
                                                int* __restrict__ row_start,
                                                int* __restrict__ bsum, int n) {
    __shared__ int sd[1024];
    int i = blockIdx.x * 1024 + threadIdx.x;
    int v = (i < n) ? counts[i] : 0;
    sd[threadIdx.x] = v;
    __syncthreads();
    for (int off = 1; off < 1024; off <<= 1) {
        int t = (threadIdx.x >= off) ? sd[threadIdx.x - off] : 0;
        __syncthreads();
        sd[threadIdx.x] += t;
        __syncthreads();
    }
    if (i < n) row_start[i] = sd[threadIdx.x] - v;
    if (threadIdx.x == 1023) bsum[blockIdx.x] = sd[1023];
}

__global__ void scan2_k(int* __restrict__ bsum, int nb) {
    int lane = threadIdx.x;
    int v = (lane < nb) ? bsum[lane] : 0;
    int orig = v;
    for (int off = 1; off < 64; off <<= 1) {
        int t = __shfl_up(v, off);
        if (lane >= off) v += t;
    }
    if (lane < nb) bsum[lane] = v - orig;
}

__global__ void scan3_k(const int* __restrict__ counts, const int* __restrict__ bsum,
                        int* __restrict__ row_start, int* __restrict__ cursor,
                        float* __restrict__ inv_deg, int n, int e) {
    int i = blockIdx.x * blockDim.x + threadIdx.x;
    if (i < n) {
        int rs = row_start[i] + bsum[i >> 10];
        row_start[i] = rs;
        cursor[i] = rs;
        inv_deg[i] = 1.0f / fmaxf((float)counts[i], 1.0f);
        if (i == 0) row_start[n] = e;
    }
}

__global__ void fill_csr_k(const int* __restrict__ esrc, const int* __restrict__ edst,
                           int* __restrict__ cursor, int* __restrict__ csr_src, int e) {
    int i = blockIdx.x * blockDim.x + threadIdx.x;
    if (i < e) {
        int pos = atomicAdd(&cursor[edst[i]], 1);
        csr_src[pos] = esrc[i];
    }
}

// ---------------- weight prep ----------------

__global__ void prep_w_k(const float* __restrict__ W1, const float* __restrict__ W2,
                         ushort* __restrict__ Wt, int K, int M) {
    int i = blockIdx.x * blockDim.x + threadIdx.x;
    int tot = 2 * M * K;
    if (i >= tot) return;
    int c = i / K, k = i - c * K;
    float v = (c < M) ? W1[(size_t)k * M + c] : W2[(size_t)k * M + (c - M)];
    Wt[i] = f2bf(v);
}

// ---------------- MFMA GEMM: cols<M -> V8 (fp8), cols>=M -> R (bf16) ----------------

template<bool A_FP32>
__global__ __launch_bounds__(256) void gemm_mfma_k(const void* __restrict__ Av, int K,
                                                   const ushort* __restrict__ Wt,
                                                   uchar* __restrict__ V8,
                                                   ushort* __restrict__ Rr,
                                                   int M, int n) {
    __shared__ __align__(16) ushort As[64 * 40];
    __shared__ __align__(16) ushort Bs[128 * 40];
    int tid = threadIdx.x;
    int row0 = blockIdx.x * 64;
    int col0 = blockIdx.y * 128;
    int lane = tid & 63, wid = tid >> 6;
    int wm = wid & 1, wn = wid >> 1;
    int lrow = lane & 15, lko = (lane >> 4) * 8;

    f32x4 acc[2][4];
    #pragma unroll
    for (int i = 0; i < 2; ++i)
        #pragma unroll
        for (int j = 0; j < 4; ++j)
            acc[i][j] = (f32x4){0.f, 0.f, 0.f, 0.f};

    for (int kc = 0; kc < K; kc += 32) {
        __syncthreads();
        if constexpr (A_FP32) {
            const float* A = (const float*)Av;
            #pragma unroll
            for (int l = tid; l < 512; l += 256) {
                int r = l >> 3, s = l & 7;
                int rg = row0 + r;
                float4 a = (rg < n) ? *(const float4*)(A + (size_t)rg * K + kc + s * 4)
                                    : make_float4(0.f, 0.f, 0.f, 0.f);
                ushort* dst = &As[r * 40 + s * 4];
                dst[0] = f2bf(a.x); dst[1] = f2bf(a.y); dst[2] = f2bf(a.z); dst[3] = f2bf(a.w);
            }
        } else {
            const ushort* A = (const ushort*)Av;
            int r = tid >> 2, s = tid & 3;
            int rg = row0 + r;
            uint4 a = (rg < n) ? *(const uint4*)(A + (size_t)rg * K + kc + s * 8)
                               : make_uint4(0u, 0u, 0u, 0u);
            *(uint4*)(&As[r * 40 + s * 8]) = a;
        }
        #pragma unroll
        for (int l = tid; l < 512; l += 256) {
            int r = l >> 2, s = l & 3;
            int cg = col0 + r;
            *(uint4*)(&Bs[r * 40 + s * 8]) = *(const uint4*)(Wt + (size_t)cg * K + kc + s * 8);
        }
        __syncthreads();

        bf16x8 af[2], bfr[4];
        #pragma unroll
        for (int i = 0; i < 2; ++i)
            af[i] = *(const bf16x8*)(&As[(wm * 32 + i * 16 + lrow) * 40 + lko]);
        #pragma unroll
        for (int j = 0; j < 4; ++j)
            bfr[j] = *(const bf16x8*)(&Bs[(wn * 64 + j * 16 + lrow) * 40 + lko]);
        #pragma unroll
        for (int i = 0; i < 2; ++i)
            #pragma unroll
            for (int j = 0; j < 4; ++j)
                acc[i][j] = __builtin_amdgcn_mfma_f32_16x16x32_bf16(af[i], bfr[j], acc[i][j], 0, 0, 0);
    }

    #pragma unroll
    for (int i = 0; i < 2; ++i) {
        int rbase = row0 + wm * 32 + i * 16 + (lane >> 4) * 4;
        #pragma unroll
        for (int j = 0; j < 4; ++j) {
            int cg = col0 + wn * 64 + j * 16 + lrow;
            #pragma unroll
            for (int q = 0; q < 4; ++q) {
                int rg = rbase + q;
                if (rg < n) {
                    float v = acc[i][j][q];
                    if (cg < M) V8[(size_t)rg * M + cg] = f2fp8(v);
                    else        Rr[(size_t)rg * M + (cg - M)] = f2bf(v);
                }
            }
        }
    }
}

// ---------------- per-dst aggregation + combine (fp8 gather operand) ----------------
// out[dst,c] = act( mean_agg(V8)[dst,c] + bias[c] + R[dst,c] )
// one wave per dst; M = VW*64. ACT: 0=none 1=relu 2=sigmoid. WF8: also write fp8 mirror.

template<int VW, int ACT, bool WF8>
__global__ __launch_bounds__(256) void agg8_k(const uchar* __restrict__ V8,
                                              const ushort* __restrict__ Rr,
                                              const float* __restrict__ bias,
                                              const float* __restrict__ inv_deg,
                                              const int* __restrict__ row_start,
                                              const int* __restrict__ csr_src,
                                              ushort* __restrict__ outb,
                                              uchar* __restrict__ out8,
                                              int ld_out, int n) {
    constexpr int M = VW * 64;
    int wid  = (blockIdx.x * blockDim.x + threadIdx.x) >> 6;
    int lane = threadIdx.x & 63;
    if (wid >= n) return;
    int dst = wid;
    int c = lane * VW;

    float acc[VW];
    #pragma unroll
    for (int q = 0; q < VW; ++q) acc[q] = 0.f;

    int s = row_start[dst], e = row_start[dst + 1];
    for (int base = s; base < e; base += 64) {
        int cnt = e - base; if (cnt > 64) cnt = 64;
        int idx = (base + lane < e) ? csr_src[base + lane] : 0;
        for (int t = 0; t < cnt; ++t) {
            int src = __shfl(idx, t);
            if constexpr (VW == 4) {
                uint u = *(const uint*)(V8 + (size_t)src * M + c);
                acc[0] += fp8dec(u & 0xFFu);
                acc[1] += fp8dec((u >> 8) & 0xFFu);
                acc[2] += fp8dec((u >> 16) & 0xFFu);
                acc[3] += fp8dec(u >> 24);
            } else if constexpr (VW == 2) {
                uint u = *(const ushort*)(V8 + (size_t)src * M + c);
                acc[0] += fp8dec(u & 0xFFu);
                acc[1] += fp8dec(u >> 8);
            } else {
                acc[0] += fp8dec(V8[(size_t)src * M + c]);
            }
        }
    }

    float inv = inv_deg[dst];
    float r[VW];
    #pragma unroll
    for (int q = 0; q < VW; ++q) {
        float v = acc[q] * inv;
        if (bias) v += bias[c + q];
        if (Rr)   v += bf2f(Rr[(size_t)dst * M + c + q]);
        if constexpr (ACT == 1) v = fmaxf(v, 0.f);
        else if constexpr (ACT == 2) v = 1.f / (1.f + expf(-v));
        r[q] = v;
    }
    if constexpr (VW == 4) {
        ushort4 o; o.x = f2bf(r[0]); o.y = f2bf(r[1]); o.z = f2bf(r[2]); o.w = f2bf(r[3]);
        *(ushort4*)((ushort*)outb + (size_t)dst * ld_out + c) = o;
    } else if constexpr (VW == 2) {
        uint o = (uint)f2bf(r[0]) | ((uint)f2bf(r[1]) << 16);
        *(uint*)((ushort*)outb + (size_t)dst * ld_out + c) = o;
    } else {
        outb[(size_t)dst * ld_out + c] = f2bf(r[0]);
    }
    if constexpr (WF8) {
        #pragma unroll
        for (int q = 0; q < VW; ++q)
            out8[(size_t)dst * M + c + q] = f2fp8(r[q]);
    }
}

// ---------------- heads + cross-entropy ----------------

template<int C>
__device__ inline float head_one(const float* __restrict__ ah, const float* __restrict__ hh,
                                 const float* __restrict__ Wl, const float* __restrict__ bl,
                                 const float* __restrict__ Wr, int label) {
    float z[C];
    #pragma unroll
    for (int c = 0; c < C; ++c) z[c] = bl[c];
    for (int d = 0; d < 64; ++d) {
        float a = ah[d], h = hh[d];
        #pragma unroll
        for (int c = 0; c < C; ++c)
            z[c] = fmaf(a, Wl[d * C + c], fmaf(h, Wr[d * C + c], z[c]));
    }
    float m = -1e30f;
    #pragma unroll
    for (int c = 0; c < C; ++c) { z[c] = 1.f / (1.f + expf(-z[c])); m = fmaxf(m, z[c]); }
    float ssum = 0.f, zl = 0.f;
    #pragma unroll
    for (int c = 0; c < C; ++c) { ssum += expf(z[c] - m); if (c == label) zl = z[c]; }
    return (logf(ssum) + m) - zl;
}

__global__ __launch_bounds__(256) void head_ce_k(const ushort* __restrict__ Ah,
                                                 const ushort* __restrict__ hk,
                                                 const float* __restrict__ Wl1, const float* __restrict__ b1, const float* __restrict__ Wr1,
                                                 const float* __restrict__ Wl2, const float* __restrict__ b2, const float* __restrict__ Wr2,
                                                 const float* __restrict__ Wl3, const float* __restrict__ b3, const float* __restrict__ Wr3,
                                                 const int* __restrict__ y,
                                                 float* __restrict__ loss_acc, int n) {
    int nidx = blockIdx.x * blockDim.x + threadIdx.x;
    float lsum = 0.f;
    if (nidx < n) {
        float ah[64], hh[64];
        const ushort* ap = Ah + (size_t)nidx * 64;
        const ushort* hp = hk + (size_t)nidx * 64;
        #pragma unroll
        for (int d = 0; d < 64; ++d) { ah[d] = bf2f(ap[d]); hh[d] = bf2f(hp[d]); }
        lsum += head_one<12>(ah, hh, Wl1, b1, Wr1, y[nidx * 3 + 0]);
        lsum += head_one<8 >(ah, hh, Wl2, b2, Wr2, y[nidx * 3 + 1]);
        lsum += head_one<5 >(ah, hh, Wl3, b3, Wr3, y[nidx * 3 + 2]);
    }
    for (int off = 32; off > 0; off >>= 1) lsum += __shfl_down(lsum, off);
    __shared__ float ssum[4];
    int wv = threadIdx.x >> 6, ln = threadIdx.x & 63;
    if (ln == 0) ssum[wv] = lsum;
    __syncthreads();
    if (threadIdx.x == 0) atomicAdd(loss_acc, ssum[0] + ssum[1] + ssum[2] + ssum[3]);
}

__global__ void finalize_k(const float* __restrict__ loss_acc, float* __restrict__ out, int n) {
    out[0] = loss_acc[0] * (1.0f / (float)n);
}

// ---------------- host ----------------

extern "C" void kernel_launch(void* const* d_in, const int* in_sizes, int n_in,
                              void* d_out, int out_size, void* d_ws, size_t ws_size,
                              hipStream_t stream) {
    const float* X    = (const float*)d_in[0];
    const int*   esrc = (const int*)d_in[1];
    const int*   edst = (const int*)d_in[2];
    const int*   y    = (const int*)d_in[3];
    const float* Wl_i[2] = {(const float*)d_in[4], (const float*)d_in[7]};
    const float* bl_i[2] = {(const float*)d_in[5], (const float*)d_in[8]};
    const float* Wr_i[2] = {(const float*)d_in[6], (const float*)d_in[9]};
    const float* Wl_m = (const float*)d_in[10], *bl_m = (const float*)d_in[11], *Wr_m = (const float*)d_in[12];
    const float* Wl_o = (const float*)d_in[13], *bl_o = (const float*)d_in[14], *Wr_o = (const float*)d_in[15];
    const float* Wl_t1 = (const float*)d_in[16], *bl_t1 = (const float*)d_in[17], *Wr_t1 = (const float*)d_in[18];
    const float* Wl_t2 = (const float*)d_in[19], *bl_t2 = (const float*)d_in[20], *Wr_t2 = (const float*)d_in[21];
    const float* Wl_t3 = (const float*)d_in[22], *bl_t3 = (const float*)d_in[23], *Wr_t3 = (const float*)d_in[24];

    const int N = NN, E = NE;
    char* p = (char*)d_ws;
    auto alloc = [&](size_t bytes) -> char* {
        char* r = p;
        p += (bytes + 255) & ~(size_t)255;
        return r;
    };
    int*    counts    = (int*)alloc((size_t)N * 4);
    int*    row_start = (int*)alloc((size_t)(N + 1) * 4);
    int*    cursor    = (int*)alloc((size_t)N * 4);
    int*    bsum      = (int*)alloc(64 * 4);
    int*    csr_src   = (int*)alloc((size_t)E * 4);
    float*  inv_deg   = (float*)alloc((size_t)N * 4);
    float*  loss_acc  = (float*)alloc(256);
    uchar*  V8   = (uchar*)alloc((size_t)N * 256);
    ushort* R    = (ushort*)alloc((size_t)N * 256 * 2);
    ushort* xk   = (ushort*)alloc((size_t)N * 256 * 2);
    ushort* hk   = (ushort*)alloc((size_t)N * 64 * 2);
    uchar*  hk8  = (uchar*)alloc((size_t)N * 64);
    ushort* Ah   = (ushort*)alloc((size_t)N * 64 * 2);
    ushort* Wt_i0 = (ushort*)alloc((size_t)256 * 128 * 2);
    ushort* Wt_i1 = (ushort*)alloc((size_t)256 * 128 * 2);
    ushort* Wt_m  = (ushort*)alloc((size_t)512 * 256 * 2);
    ushort* Wt_o  = (ushort*)alloc((size_t)128 * 256 * 2);

    hipMemsetAsync(counts, 0, (size_t)N * 4, stream);
    hipMemsetAsync(loss_acc, 0, 4, stream);
    count_edges_k<<<(E + 255) / 256, 256, 0, stream>>>(edst, counts, E);
    const int NB = (N + 1023) / 1024;
    scan1_k<<<NB, 1024, 0, stream>>>(counts, row_start, bsum, N);
    scan2_k<<<1, 64, 0, stream>>>(bsum, NB);
    scan3_k<<<(N + 255) / 256, 256, 0, stream>>>(counts, bsum, row_start, cursor, inv_deg, N, E);
    fill_csr_k<<<(E + 255) / 256, 256, 0, stream>>>(esrc, edst, cursor, csr_src, E);

    prep_w_k<<<(2 * 128 * 128 + 255) / 256, 256, 0, stream>>>(Wl_i[0], Wr_i[0], Wt_i0, 128, 128);
    prep_w_k<<<(2 * 128 * 128 + 255) / 256, 256, 0, stream>>>(Wl_i[1], Wr_i[1], Wt_i1, 128, 128);
    prep_w_k<<<(2 * 256 * 256 + 255) / 256, 256, 0, stream>>>(Wl_m, Wr_m, Wt_m, 256, 256);
    prep_w_k<<<(2 * 256 * 64 + 255) / 256, 256, 0, stream>>>(Wl_o, Wr_o, Wt_o, 256, 64);

    const int RB = (N + 63) / 64;
    const int AGB = (N + 3) / 4;   // agg blocks: 4 waves of 1 dst each
    const ushort* Wt_i[2] = {Wt_i0, Wt_i1};

    for (int k = 0; k < 2; ++k) {
        for (int ch = 0; ch < 2; ++ch) {
            const float* Xc = X + (size_t)(k * 2 + ch) * N * 128;
            gemm_mfma_k<true><<<dim3(RB, 2), 256, 0, stream>>>(Xc, 128, Wt_i[ch], V8, R, 128, N);
            agg8_k<2, 1, false><<<AGB, 256, 0, stream>>>(V8, R, bl_i[ch], inv_deg, row_start, csr_src,
                                                         xk + ch * 128, nullptr, 256, N);
        }
        gemm_mfma_k<false><<<dim3(RB, 4), 256, 0, stream>>>(xk, 256, Wt_m, V8, R, 256, N);
        agg8_k<4, 1, false><<<AGB, 256, 0, stream>>>(V8, R, bl_m, inv_deg, row_start, csr_src,
                                                     xk, nullptr, 256, N);
        gemm_mfma_k<false><<<dim3(RB, 1), 256, 0, stream>>>(xk, 256, Wt_o, V8, R, 64, N);
        agg8_k<1, 2, true><<<AGB, 256, 0, stream>>>(V8, R, bl_o, inv_deg, row_start, csr_src,
                                                    hk, hk8, 64, N);
        agg8_k<1, 0, false><<<AGB, 256, 0, stream>>>(hk8, nullptr, nullptr, inv_deg, row_start, csr_src,
                                                     Ah, nullptr, 64, N);
        head_ce_k<<<(N + 255) / 256, 256, 0, stream>>>(Ah, hk,
            Wl_t1 + (size_t)k * 64 * 12, bl_t1 + (size_t)k * 12, Wr_t1 + (size_t)k * 64 * 12,
            Wl_t2 + (size_t)k * 64 * 8,  bl_t2 + (size_t)k * 8,  Wr_t2 + (size_t)k * 64 * 8,
            Wl_t3 + (size_t)k * 64 * 5,  bl_t3 + (size_t)k * 5,  Wr_t3 + (size_t)k * 64 * 5,
            y + (size_t)k * N * 3, loss_acc, N);
    }
    finalize_k<<<1, 1, 0, stream>>>(loss_acc, (float*)d_out, N);
}

// Round 5
// 938.379 us; speedup vs baseline: 2.1095x; 1.0383x over previous
//
#include <hip/hip_runtime.h>
#include <math.h>

#define NN 50000
#define NE 800000

typedef short bf16x8 __attribute__((ext_vector_type(8)));
typedef float f32x4 __attribute__((ext_vector_type(4)));
typedef float f32x2 __attribute__((ext_vector_type(2)));

__device__ inline ushort f2bf(float f) {
    union { float f; uint u; } v; v.f = f;
    uint r = v.u + 0x7FFFu + ((v.u >> 16) & 1u);
    return (ushort)(r >> 16);
}
__device__ inline float bf2f(ushort h) {
    union { uint u; float f; } v; v.u = ((uint)h) << 16;
    return v.f;
}
// fp8 e4m3fn software codecs (bit-exact OCP e4m3fn incl. denormals)
__device__ inline uchar f2fp8(float f) {
    float a = fminf(fabsf(f), 448.f);
    union { float f; uint u; } v; v.f = a * 7.52316384526264e-37f;  // *2^-120
    uint r = (v.u + 0x7FFFFu + ((v.u >> 20) & 1u)) >> 20;           // RNE to e4m3 magnitude
    if (r > 0x7Eu) r = 0x7Eu;                                        // never emit NaN code
    union { float f; uint u; } s; s.f = f;
    return (uchar)(r | ((s.u >> 31) << 7));
}
__device__ inline float fp8dec(uint b) {
    union { uint u; float f; } t; t.u = (b & 0x7Fu) << 20;
    union { float f; uint u; } o; o.f = t.f * 1.3292279957849159e36f;  // *2^120
    o.u |= (b & 0x80u) << 24;
    return o.f;
}

// ---------------- CSR build ----------------

__global__ void count_edges_k(const int* __restrict__ edst, int* __restrict__ counts, int e) {
    int i = blockIdx.x * blockDim.x + threadIdx.x;
    if (i < e) atomicAdd(&counts[edst[i]], 1);
}

__global__ __launch_bounds__(1024) void scan1_k(const int* __restrict__ counts,
                                                int* __restrict__ row_start,
                                                int* __restrict__ bsum, int n) {
    __shared__ int sd[1024];
    int i = blockIdx.x * 1024 + threadIdx.x;
    int v = (i < n) ? counts[i] : 0;
    sd[threadIdx.x] = v;
    __syncthreads();
    for (int off = 1; off < 1024; off <<= 1) {
        int t = (threadIdx.x >= off) ? sd[threadIdx.x - off] : 0;
        __syncthreads();
        sd[threadIdx.x] += t;
        __syncthreads();
    }
    if (i < n) row_start[i] = sd[threadIdx.x] - v;
    if (threadIdx.x == 1023) bsum[blockIdx.x] = sd[1023];
}

__global__ void scan2_k(int* __restrict__ bsum, int nb) {
    int lane = threadIdx.x;
    int v = (lane < nb) ? bsum[lane] : 0;
    int orig = v;
    for (int off = 1; off < 64; off <<= 1) {
        int t = __shfl_up(v, off);
        if (lane >= off) v += t;
    }
    if (lane < nb) bsum[lane] = v - orig;
}

__global__ void scan3_k(const int* __restrict__ counts, const int* __restrict__ bsum,
                        int* __restrict__ row_start, int* __restrict__ cursor,
                        float* __restrict__ inv_deg, int n, int e) {
    int i = blockIdx.x * blockDim.x + threadIdx.x;
    if (i < n) {
        int rs = row_start[i] + bsum[i >> 10];
        row_start[i] = rs;
        cursor[i] = rs;
        inv_deg[i] = 1.0f / fmaxf((float)counts[i], 1.0f);
        if (i == 0) row_start[n] = e;
    }
}

__global__ void fill_csr_k(const int* __restrict__ esrc, const int* __restrict__ edst,
                           int* __restrict__ cursor, int* __restrict__ csr_src, int e) {
    int i = blockIdx.x * blockDim.x + threadIdx.x;
    if (i < e) {
        int pos = atomicAdd(&cursor[edst[i]], 1);
        csr_src[pos] = esrc[i];
    }
}

// ---------------- weight prep ----------------

__global__ void prep_w_k(const float* __restrict__ W1, const float* __restrict__ W2,
                         ushort* __restrict__ Wt, int K, int M) {
    int i = blockIdx.x * blockDim.x + threadIdx.x;
    int tot = 2 * M * K;
    if (i >= tot) return;
    int c = i / K, k = i - c * K;
    float v = (c < M) ? W1[(size_t)k * M + c] : W2[(size_t)k * M + (c - M)];
    Wt[i] = f2bf(v);
}

// ---------------- MFMA GEMM: cols<M -> V8 (fp8), cols>=M -> R (bf16) ----------------

template<bool A_FP32>
__global__ __launch_bounds__(256) void gemm_mfma_k(const void* __restrict__ Av, int K,
                                                   const ushort* __restrict__ Wt,
                                                   uchar* __restrict__ V8,
                                                   ushort* __restrict__ Rr,
                                                   int M, int n) {
    __shared__ __align__(16) ushort As[64 * 40];
    __shared__ __align__(16) ushort Bs[128 * 40];
    int tid = threadIdx.x;
    int row0 = blockIdx.x * 64;
    int col0 = blockIdx.y * 128;
    int lane = tid & 63, wid = tid >> 6;
    int wm = wid & 1, wn = wid >> 1;
    int lrow = lane & 15, lko = (lane >> 4) * 8;

    f32x4 acc[2][4];
    #pragma unroll
    for (int i = 0; i < 2; ++i)
        #pragma unroll
        for (int j = 0; j < 4; ++j)
            acc[i][j] = (f32x4){0.f, 0.f, 0.f, 0.f};

    for (int kc = 0; kc < K; kc += 32) {
        __syncthreads();
        if constexpr (A_FP32) {
            const float* A = (const float*)Av;
            #pragma unroll
            for (int l = tid; l < 512; l += 256) {
                int r = l >> 3, s = l & 7;
                int rg = row0 + r;
                float4 a = (rg < n) ? *(const float4*)(A + (size_t)rg * K + kc + s * 4)
                                    : make_float4(0.f, 0.f, 0.f, 0.f);
                ushort* dst = &As[r * 40 + s * 4];
                dst[0] = f2bf(a.x); dst[1] = f2bf(a.y); dst[2] = f2bf(a.z); dst[3] = f2bf(a.w);
            }
        } else {
            const ushort* A = (const ushort*)Av;
            int r = tid >> 2, s = tid & 3;
            int rg = row0 + r;
            uint4 a = (rg < n) ? *(const uint4*)(A + (size_t)rg * K + kc + s * 8)
                               : make_uint4(0u, 0u, 0u, 0u);
            *(uint4*)(&As[r * 40 + s * 8]) = a;
        }
        #pragma unroll
        for (int l = tid; l < 512; l += 256) {
            int r = l >> 2, s = l & 3;
            int cg = col0 + r;
            *(uint4*)(&Bs[r * 40 + s * 8]) = *(const uint4*)(Wt + (size_t)cg * K + kc + s * 8);
        }
        __syncthreads();

        bf16x8 af[2], bfr[4];
        #pragma unroll
        for (int i = 0; i < 2; ++i)
            af[i] = *(const bf16x8*)(&As[(wm * 32 + i * 16 + lrow) * 40 + lko]);
        #pragma unroll
        for (int j = 0; j < 4; ++j)
            bfr[j] = *(const bf16x8*)(&Bs[(wn * 64 + j * 16 + lrow) * 40 + lko]);
        #pragma unroll
        for (int i = 0; i < 2; ++i)
            #pragma unroll
            for (int j = 0; j < 4; ++j)
                acc[i][j] = __builtin_amdgcn_mfma_f32_16x16x32_bf16(af[i], bfr[j], acc[i][j], 0, 0, 0);
    }

    #pragma unroll
    for (int i = 0; i < 2; ++i) {
        int rbase = row0 + wm * 32 + i * 16 + (lane >> 4) * 4;
        #pragma unroll
        for (int j = 0; j < 4; ++j) {
            int cg = col0 + wn * 64 + j * 16 + lrow;
            #pragma unroll
            for (int q = 0; q < 4; ++q) {
                int rg = rbase + q;
                if (rg < n) {
                    float v = acc[i][j][q];
                    if (cg < M) V8[(size_t)rg * M + cg] = f2fp8(v);
                    else        Rr[(size_t)rg * M + (cg - M)] = f2bf(v);
                }
            }
        }
    }
}

// ---------------- per-dst aggregation + combine (fp8 gather operand) ----------------

template<int VW, int ACT, bool WF8>
__global__ __launch_bounds__(256) void agg8_k(const uchar* __restrict__ V8,
                                              const ushort* __restrict__ Rr,
                                              const float* __restrict__ bias,
                                              const float* __restrict__ inv_deg,
                                              const int* __restrict__ row_start,
                                              const int* __restrict__ csr_src,
                                              ushort* __restrict__ outb,
                                              uchar* __restrict__ out8,
                                              int ld_out, int n) {
    constexpr int M = VW * 64;
    int wid  = (blockIdx.x * blockDim.x + threadIdx.x) >> 6;
    int lane = threadIdx.x & 63;
    if (wid >= n) return;
    int dst = wid;
    int c = lane * VW;

    float acc[VW];
    #pragma unroll
    for (int q = 0; q < VW; ++q) acc[q] = 0.f;

    int s = row_start[dst], e = row_start[dst + 1];
    for (int base = s; base < e; base += 64) {
        int cnt = e - base; if (cnt > 64) cnt = 64;
        int idx = (base + lane < e) ? csr_src[base + lane] : 0;
        for (int t = 0; t < cnt; ++t) {
            int src = __shfl(idx, t);
            if constexpr (VW == 4) {
                uint u = *(const uint*)(V8 + (size_t)src * M + c);
#if __has_builtin(__builtin_amdgcn_cvt_pk_f32_fp8)
                f32x2 lo = __builtin_amdgcn_cvt_pk_f32_fp8((int)u, false);
                f32x2 hi = __builtin_amdgcn_cvt_pk_f32_fp8((int)u, true);
                acc[0] += lo[0]; acc[1] += lo[1]; acc[2] += hi[0]; acc[3] += hi[1];
#else
                acc[0] += fp8dec(u & 0xFFu);
                acc[1] += fp8dec((u >> 8) & 0xFFu);
                acc[2] += fp8dec((u >> 16) & 0xFFu);
                acc[3] += fp8dec(u >> 24);
#endif
            } else if constexpr (VW == 2) {
                uint u = *(const ushort*)(V8 + (size_t)src * M + c);
#if __has_builtin(__builtin_amdgcn_cvt_pk_f32_fp8)
                f32x2 lo = __builtin_amdgcn_cvt_pk_f32_fp8((int)u, false);
                acc[0] += lo[0]; acc[1] += lo[1];
#else
                acc[0] += fp8dec(u & 0xFFu);
                acc[1] += fp8dec(u >> 8);
#endif
            } else {
                acc[0] += fp8dec(V8[(size_t)src * M + c]);
            }
        }
    }

    float inv = inv_deg[dst];
    float r[VW];
    #pragma unroll
    for (int q = 0; q < VW; ++q) {
        float v = acc[q] * inv;
        if (bias) v += bias[c + q];
        if (Rr)   v += bf2f(Rr[(size_t)dst * M + c + q]);
        if constexpr (ACT == 1) v = fmaxf(v, 0.f);
        else if constexpr (ACT == 2) v = 1.f / (1.f + expf(-v));
        r[q] = v;
    }
    if constexpr (VW == 4) {
        ushort4 o; o.x = f2bf(r[0]); o.y = f2bf(r[1]); o.z = f2bf(r[2]); o.w = f2bf(r[3]);
        *(ushort4*)((ushort*)outb + (size_t)dst * ld_out + c) = o;
    } else if constexpr (VW == 2) {
        uint o = (uint)f2bf(r[0]) | ((uint)f2bf(r[1]) << 16);
        *(uint*)((ushort*)outb + (size_t)dst * ld_out + c) = o;
    } else {
        outb[(size_t)dst * ld_out + c] = f2bf(r[0]);
    }
    if constexpr (WF8) {
        #pragma unroll
        for (int q = 0; q < VW; ++q)
            out8[(size_t)dst * M + c + q] = f2fp8(r[q]);
    }
}

// ---------------- heads + cross-entropy (spill-free: one pass, 25 live accumulators) ----

template<int C>
__device__ inline float ce_from_z(float* z, int label) {
    float m = -1e30f;
    #pragma unroll
    for (int c = 0; c < C; ++c) { z[c] = 1.f / (1.f + expf(-z[c])); m = fmaxf(m, z[c]); }
    float ssum = 0.f, zl = 0.f;
    #pragma unroll
    for (int c = 0; c < C; ++c) { ssum += expf(z[c] - m); if (c == label) zl = z[c]; }
    return (logf(ssum) + m) - zl;   // = -logp[label]
}

__global__ __launch_bounds__(256) void head_ce_k(const ushort* __restrict__ Ah,
                                                 const ushort* __restrict__ hk,
                                                 const float* __restrict__ Wl1, const float* __restrict__ b1, const float* __restrict__ Wr1,
                                                 const float* __restrict__ Wl2, const float* __restrict__ b2, const float* __restrict__ Wr2,
                                                 const float* __restrict__ Wl3, const float* __restrict__ b3, const float* __restrict__ Wr3,
                                                 const int* __restrict__ y,
                                                 float* __restrict__ loss_acc, int n) {
    int nidx = blockIdx.x * blockDim.x + threadIdx.x;
    float lsum = 0.f;
    if (nidx < n) {
        float z0[12], z1[8], z2[5];
        #pragma unroll
        for (int c = 0; c < 12; ++c) z0[c] = b1[c];
        #pragma unroll
        for (int c = 0; c < 8; ++c) z1[c] = b2[c];
        #pragma unroll
        for (int c = 0; c < 5; ++c) z2[c] = b3[c];

        const ushort* ap = Ah + (size_t)nidx * 64;
        const ushort* hp = hk + (size_t)nidx * 64;
        for (int d8 = 0; d8 < 64; d8 += 8) {
            uint4 ua = *(const uint4*)(ap + d8);
            uint4 uh = *(const uint4*)(hp + d8);
            uint aw[4] = {ua.x, ua.y, ua.z, ua.w};
            uint hw[4] = {uh.x, uh.y, uh.z, uh.w};
            #pragma unroll
            for (int p = 0; p < 4; ++p) {
                #pragma unroll
                for (int half = 0; half < 2; ++half) {
                    int d = d8 + p * 2 + half;
                    float av = bf2f((ushort)(half ? (aw[p] >> 16) : (aw[p] & 0xFFFF)));
                    float hv = bf2f((ushort)(half ? (hw[p] >> 16) : (hw[p] & 0xFFFF)));
                    #pragma unroll
                    for (int c = 0; c < 12; ++c)
                        z0[c] = fmaf(av, Wl1[d * 12 + c], fmaf(hv, Wr1[d * 12 + c], z0[c]));
                    #pragma unroll
                    for (int c = 0; c < 8; ++c)
                        z1[c] = fmaf(av, Wl2[d * 8 + c], fmaf(hv, Wr2[d * 8 + c], z1[c]));
                    #pragma unroll
                    for (int c = 0; c < 5; ++c)
                        z2[c] = fmaf(av, Wl3[d * 5 + c], fmaf(hv, Wr3[d * 5 + c], z2[c]));
                }
            }
        }
        lsum  = ce_from_z<12>(z0, y[nidx * 3 + 0]);
        lsum += ce_from_z<8 >(z1, y[nidx * 3 + 1]);
        lsum += ce_from_z<5 >(z2, y[nidx * 3 + 2]);
    }
    for (int off = 32; off > 0; off >>= 1) lsum += __shfl_down(lsum, off);
    __shared__ float ssum[4];
    int wv = threadIdx.x >> 6, ln = threadIdx.x & 63;
    if (ln == 0) ssum[wv] = lsum;
    __syncthreads();
    if (threadIdx.x == 0) atomicAdd(loss_acc, ssum[0] + ssum[1] + ssum[2] + ssum[3]);
}

__global__ void finalize_k(const float* __restrict__ loss_acc, float* __restrict__ out, int n) {
    out[0] = loss_acc[0] * (1.0f / (float)n);
}

// ---------------- host ----------------

extern "C" void kernel_launch(void* const* d_in, const int* in_sizes, int n_in,
                              void* d_out, int out_size, void* d_ws, size_t ws_size,
                              hipStream_t stream) {
    const float* X    = (const float*)d_in[0];
    const int*   esrc = (const int*)d_in[1];
    const int*   edst = (const int*)d_in[2];
    const int*   y    = (const int*)d_in[3];
    const float* Wl_i[2] = {(const float*)d_in[4], (const float*)d_in[7]};
    const float* bl_i[2] = {(const float*)d_in[5], (const float*)d_in[8]};
    const float* Wr_i[2] = {(const float*)d_in[6], (const float*)d_in[9]};
    const float* Wl_m = (const float*)d_in[10], *bl_m = (const float*)d_in[11], *Wr_m = (const float*)d_in[12];
    const float* Wl_o = (const float*)d_in[13], *bl_o = (const float*)d_in[14], *Wr_o = (const float*)d_in[15];
    const float* Wl_t1 = (const float*)d_in[16], *bl_t1 = (const float*)d_in[17], *Wr_t1 = (const float*)d_in[18];
    const float* Wl_t2 = (const float*)d_in[19], *bl_t2 = (const float*)d_in[20], *Wr_t2 = (const float*)d_in[21];
    const float* Wl_t3 = (const float*)d_in[22], *bl_t3 = (const float*)d_in[23], *Wr_t3 = (const float*)d_in[24];

    const int N = NN, E = NE;
    char* p = (char*)d_ws;
    auto alloc = [&](size_t bytes) -> char* {
        char* r = p;
        p += (bytes + 255) & ~(size_t)255;
        return r;
    };
    int*    counts    = (int*)alloc((size_t)N * 4);
    int*    row_start = (int*)alloc((size_t)(N + 1) * 4);
    int*    cursor    = (int*)alloc((size_t)N * 4);
    int*    bsum      = (int*)alloc(64 * 4);
    int*    csr_src   = (int*)alloc((size_t)E * 4);
    float*  inv_deg   = (float*)alloc((size_t)N * 4);
    float*  loss_acc  = (float*)alloc(256);
    uchar*  V8   = (uchar*)alloc((size_t)N * 256);
    ushort* R    = (ushort*)alloc((size_t)N * 256 * 2);
    ushort* xk   = (ushort*)alloc((size_t)N * 256 * 2);
    ushort* hk   = (ushort*)alloc((size_t)N * 64 * 2);
    uchar*  hk8  = (uchar*)alloc((size_t)N * 64);
    ushort* Ah   = (ushort*)alloc((size_t)N * 64 * 2);
    ushort* Wt_i0 = (ushort*)alloc((size_t)256 * 128 * 2);
    ushort* Wt_i1 = (ushort*)alloc((size_t)256 * 128 * 2);
    ushort* Wt_m  = (ushort*)alloc((size_t)512 * 256 * 2);
    ushort* Wt_o  = (ushort*)alloc((size_t)128 * 256 * 2);

    hipMemsetAsync(counts, 0, (size_t)N * 4, stream);
    hipMemsetAsync(loss_acc, 0, 4, stream);
    count_edges_k<<<(E + 255) / 256, 256, 0, stream>>>(edst, counts, E);
    const int NB = (N + 1023) / 1024;
    scan1_k<<<NB, 1024, 0, stream>>>(counts, row_start, bsum, N);
    scan2_k<<<1, 64, 0, stream>>>(bsum, NB);
    scan3_k<<<(N + 255) / 256, 256, 0, stream>>>(counts, bsum, row_start, cursor, inv_deg, N, E);
    fill_csr_k<<<(E + 255) / 256, 256, 0, stream>>>(esrc, edst, cursor, csr_src, E);

    prep_w_k<<<(2 * 128 * 128 + 255) / 256, 256, 0, stream>>>(Wl_i[0], Wr_i[0], Wt_i0, 128, 128);
    prep_w_k<<<(2 * 128 * 128 + 255) / 256, 256, 0, stream>>>(Wl_i[1], Wr_i[1], Wt_i1, 128, 128);
    prep_w_k<<<(2 * 256 * 256 + 255) / 256, 256, 0, stream>>>(Wl_m, Wr_m, Wt_m, 256, 256);
    prep_w_k<<<(2 * 256 * 64 + 255) / 256, 256, 0, stream>>>(Wl_o, Wr_o, Wt_o, 256, 64);

    const int RB = (N + 63) / 64;
    const int AGB = (N + 3) / 4;
    const ushort* Wt_i[2] = {Wt_i0, Wt_i1};

    for (int k = 0; k < 2; ++k) {
        for (int ch = 0; ch < 2; ++ch) {
            const float* Xc = X + (size_t)(k * 2 + ch) * N * 128;
            gemm_mfma_k<true><<<dim3(RB, 2), 256, 0, stream>>>(Xc, 128, Wt_i[ch], V8, R, 128, N);
            agg8_k<2, 1, false><<<AGB, 256, 0, stream>>>(V8, R, bl_i[ch], inv_deg, row_start, csr_src,
                                                         xk + ch * 128, nullptr, 256, N);
        }
        gemm_mfma_k<false><<<dim3(RB, 4), 256, 0, stream>>>(xk, 256, Wt_m, V8, R, 256, N);
        agg8_k<4, 1, false><<<AGB, 256, 0, stream>>>(V8, R, bl_m, inv_deg, row_start, csr_src,
                                                     xk, nullptr, 256, N);
        gemm_mfma_k<false><<<dim3(RB, 1), 256, 0, stream>>>(xk, 256, Wt_o, V8, R, 64, N);
        agg8_k<1, 2, true><<<AGB, 256, 0, stream>>>(V8, R, bl_o, inv_deg, row_start, csr_src,
                                                    hk, hk8, 64, N);
        agg8_k<1, 0, false><<<AGB, 256, 0, stream>>>(hk8, nullptr, nullptr, inv_deg, row_start, csr_src,
                                                     Ah, nullptr, 64, N);
        head_ce_k<<<(N + 255) / 256, 256, 0, stream>>>(Ah, hk,
            Wl_t1 + (size_t)k * 64 * 12, bl_t1 + (size_t)k * 12, Wr_t1 + (size_t)k * 64 * 12,
            Wl_t2 + (size_t)k * 64 * 8,  bl_t2 + (size_t)k * 8,  Wr_t2 + (size_t)k * 64 * 8,
            Wl_t3 + (size_t)k * 64 * 5,  bl_t3 + (size_t)k * 5,  Wr_t3 + (size_t)k * 64 * 5,
            y + (size_t)k * N * 3, loss_acc, N);
    }
    finalize_k<<<1, 1, 0, stream>>>(loss_acc, (float*)d_out, N);
}

// Round 6
// 770.953 us; speedup vs baseline: 2.5676x; 1.2172x over previous
//
#include <hip/hip_runtime.h>
#include <math.h>

#define NN 50000
#define NE 800000

typedef short bf16x8 __attribute__((ext_vector_type(8)));
typedef float f32x4 __attribute__((ext_vector_type(4)));
typedef float f32x2 __attribute__((ext_vector_type(2)));

__device__ inline ushort f2bf(float f) {
    union { float f; uint u; } v; v.f = f;
    uint r = v.u + 0x7FFFu + ((v.u >> 16) & 1u);
    return (ushort)(r >> 16);
}
__device__ inline float bf2f(ushort h) {
    union { uint u; float f; } v; v.u = ((uint)h) << 16;
    return v.f;
}
// fp8 e4m3fn software codecs (bit-exact OCP e4m3fn incl. denormals)
__device__ inline uchar f2fp8(float f) {
    float a = fminf(fabsf(f), 448.f);
    union { float f; uint u; } v; v.f = a * 7.52316384526264e-37f;  // *2^-120
    uint r = (v.u + 0x7FFFFu + ((v.u >> 20) & 1u)) >> 20;           // RNE to e4m3 magnitude
    if (r > 0x7Eu) r = 0x7Eu;                                        // never emit NaN code
    union { float f; uint u; } s; s.f = f;
    return (uchar)(r | ((s.u >> 31) << 7));
}
__device__ inline float fp8dec(uint b) {
    union { uint u; float f; } t; t.u = (b & 0x7Fu) << 20;
    union { float f; uint u; } o; o.f = t.f * 1.3292279957849159e36f;  // *2^120
    o.u |= (b & 0x80u) << 24;
    return o.f;
}
// decode 4 fp8 (packed in uint) and accumulate
__device__ inline void acc_fp8x4(float* acc, uint u) {
#if __has_builtin(__builtin_amdgcn_cvt_pk_f32_fp8)
    f32x2 lo = __builtin_amdgcn_cvt_pk_f32_fp8((int)u, false);
    f32x2 hi = __builtin_amdgcn_cvt_pk_f32_fp8((int)u, true);
    acc[0] += lo[0]; acc[1] += lo[1]; acc[2] += hi[0]; acc[3] += hi[1];
#else
    acc[0] += fp8dec(u & 0xFFu);
    acc[1] += fp8dec((u >> 8) & 0xFFu);
    acc[2] += fp8dec((u >> 16) & 0xFFu);
    acc[3] += fp8dec(u >> 24);
#endif
}

// ---------------- CSR build ----------------

__global__ void count_edges_k(const int* __restrict__ edst, int* __restrict__ counts, int e) {
    int i = blockIdx.x * blockDim.x + threadIdx.x;
    if (i < e) atomicAdd(&counts[edst[i]], 1);
}

__global__ __launch_bounds__(1024) void scan1_k(const int* __restrict__ counts,
                                                int* __restrict__ row_start,
                                                int* __restrict__ bsum, int n) {
    __shared__ int sd[1024];
    int i = blockIdx.x * 1024 + threadIdx.x;
    int v = (i < n) ? counts[i] : 0;
    sd[threadIdx.x] = v;
    __syncthreads();
    for (int off = 1; off < 1024; off <<= 1) {
        int t = (threadIdx.x >= off) ? sd[threadIdx.x - off] : 0;
        __syncthreads();
        sd[threadIdx.x] += t;
        __syncthreads();
    }
    if (i < n) row_start[i] = sd[threadIdx.x] - v;
    if (threadIdx.x == 1023) bsum[blockIdx.x] = sd[1023];
}

__global__ void scan2_k(int* __restrict__ bsum, int nb) {
    int lane = threadIdx.x;
    int v = (lane < nb) ? bsum[lane] : 0;
    int orig = v;
    for (int off = 1; off < 64; off <<= 1) {
        int t = __shfl_up(v, off);
        if (lane >= off) v += t;
    }
    if (lane < nb) bsum[lane] = v - orig;
}

__global__ void scan3_k(const int* __restrict__ counts, const int* __restrict__ bsum,
                        int* __restrict__ row_start, int* __restrict__ cursor,
                        float* __restrict__ inv_deg, int n, int e) {
    int i = blockIdx.x * blockDim.x + threadIdx.x;
    if (i < n) {
        int rs = row_start[i] + bsum[i >> 10];
        row_start[i] = rs;
        cursor[i] = rs;
        inv_deg[i] = 1.0f / fmaxf((float)counts[i], 1.0f);
        if (i == 0) row_start[n] = e;
    }
}

__global__ void fill_csr_k(const int* __restrict__ esrc, const int* __restrict__ edst,
                           int* __restrict__ cursor, int* __restrict__ csr_src, int e) {
    int i = blockIdx.x * blockDim.x + threadIdx.x;
    if (i < e) {
        int pos = atomicAdd(&cursor[edst[i]], 1);
        csr_src[pos] = esrc[i];
    }
}

// ---------------- weight prep ----------------

__global__ void prep_w_k(const float* __restrict__ W1, const float* __restrict__ W2,
                         ushort* __restrict__ Wt, int K, int M) {
    int i = blockIdx.x * blockDim.x + threadIdx.x;
    int tot = 2 * M * K;
    if (i >= tot) return;
    int c = i / K, k = i - c * K;
    float v = (c < M) ? W1[(size_t)k * M + c] : W2[(size_t)k * M + (c - M)];
    Wt[i] = f2bf(v);
}

// ---------------- MFMA GEMM: cols<M -> V8 (fp8), cols>=M -> R (bf16) ----------------

template<bool A_FP32>
__global__ __launch_bounds__(256) void gemm_mfma_k(const void* __restrict__ Av, int K,
                                                   const ushort* __restrict__ Wt,
                                                   uchar* __restrict__ V8,
                                                   ushort* __restrict__ Rr,
                                                   int M, int n) {
    __shared__ __align__(16) ushort As[64 * 40];
    __shared__ __align__(16) ushort Bs[128 * 40];
    int tid = threadIdx.x;
    int row0 = blockIdx.x * 64;
    int col0 = blockIdx.y * 128;
    int lane = tid & 63, wid = tid >> 6;
    int wm = wid & 1, wn = wid >> 1;
    int lrow = lane & 15, lko = (lane >> 4) * 8;

    f32x4 acc[2][4];
    #pragma unroll
    for (int i = 0; i < 2; ++i)
        #pragma unroll
        for (int j = 0; j < 4; ++j)
            acc[i][j] = (f32x4){0.f, 0.f, 0.f, 0.f};

    for (int kc = 0; kc < K; kc += 32) {
        __syncthreads();
        if constexpr (A_FP32) {
            const float* A = (const float*)Av;
            #pragma unroll
            for (int l = tid; l < 512; l += 256) {
                int r = l >> 3, s = l & 7;
                int rg = row0 + r;
                float4 a = (rg < n) ? *(const float4*)(A + (size_t)rg * K + kc + s * 4)
                                    : make_float4(0.f, 0.f, 0.f, 0.f);
                ushort* dst = &As[r * 40 + s * 4];
                dst[0] = f2bf(a.x); dst[1] = f2bf(a.y); dst[2] = f2bf(a.z); dst[3] = f2bf(a.w);
            }
        } else {
            const ushort* A = (const ushort*)Av;
            int r = tid >> 2, s = tid & 3;
            int rg = row0 + r;
            uint4 a = (rg < n) ? *(const uint4*)(A + (size_t)rg * K + kc + s * 8)
                               : make_uint4(0u, 0u, 0u, 0u);
            *(uint4*)(&As[r * 40 + s * 8]) = a;
        }
        #pragma unroll
        for (int l = tid; l < 512; l += 256) {
            int r = l >> 2, s = l & 3;
            int cg = col0 + r;
            *(uint4*)(&Bs[r * 40 + s * 8]) = *(const uint4*)(Wt + (size_t)cg * K + kc + s * 8);
        }
        __syncthreads();

        bf16x8 af[2], bfr[4];
        #pragma unroll
        for (int i = 0; i < 2; ++i)
            af[i] = *(const bf16x8*)(&As[(wm * 32 + i * 16 + lrow) * 40 + lko]);
        #pragma unroll
        for (int j = 0; j < 4; ++j)
            bfr[j] = *(const bf16x8*)(&Bs[(wn * 64 + j * 16 + lrow) * 40 + lko]);
        #pragma unroll
        for (int i = 0; i < 2; ++i)
            #pragma unroll
            for (int j = 0; j < 4; ++j)
                acc[i][j] = __builtin_amdgcn_mfma_f32_16x16x32_bf16(af[i], bfr[j], acc[i][j], 0, 0, 0);
    }

    #pragma unroll
    for (int i = 0; i < 2; ++i) {
        int rbase = row0 + wm * 32 + i * 16 + (lane >> 4) * 4;
        #pragma unroll
        for (int j = 0; j < 4; ++j) {
            int cg = col0 + wn * 64 + j * 16 + lrow;
            #pragma unroll
            for (int q = 0; q < 4; ++q) {
                int rg = rbase + q;
                if (rg < n) {
                    float v = acc[i][j][q];
                    if (cg < M) V8[(size_t)rg * M + cg] = f2fp8(v);
                    else        Rr[(size_t)rg * M + (cg - M)] = f2bf(v);
                }
            }
        }
    }
}

// ---------------- per-dst aggregation + combine (fp8 gather, MLP-optimized) ----------------
// One wave per dst. Wave split into EPW=64*8/M edge slots; each LPE=M/8 lane group
// loads one edge's row slice as uint2 (8 fp8). 4 edge-groups unrolled -> >=4 loads in flight.

template<int M, int ACT, bool WF8>
__global__ __launch_bounds__(256) void agg8_k(const uchar* __restrict__ V8,
                                              const ushort* __restrict__ Rr,
                                              const float* __restrict__ bias,
                                              const float* __restrict__ inv_deg,
                                              const int* __restrict__ row_start,
                                              const int* __restrict__ csr_src,
                                              ushort* __restrict__ outb,
                                              uchar* __restrict__ out8,
                                              int ld_out, int n) {
    constexpr int LPE = M / 8;    // lanes per edge
    constexpr int EPW = 64 / LPE; // edge slots per wave
    int wid  = (blockIdx.x * blockDim.x + threadIdx.x) >> 6;
    int lane = threadIdx.x & 63;
    if (wid >= n) return;
    int dst   = wid;
    int subl  = lane & (LPE - 1);
    int eslot = lane / LPE;
    int c0 = subl * 8;

    float acc[8];
    #pragma unroll
    for (int q = 0; q < 8; ++q) acc[q] = 0.f;

    int s = row_start[dst], e = row_start[dst + 1];
    for (int g = s; g < e; g += 4 * EPW) {
        int t0 = g + 0 * EPW + eslot;
        int t1 = g + 1 * EPW + eslot;
        int t2 = g + 2 * EPW + eslot;
        int t3 = g + 3 * EPW + eslot;
        // index loads (same addr across each LPE lane group -> L1 broadcast)
        int s0 = (t0 < e) ? csr_src[t0] : -1;
        int s1 = (t1 < e) ? csr_src[t1] : -1;
        int s2 = (t2 < e) ? csr_src[t2] : -1;
        int s3 = (t3 < e) ? csr_src[t3] : -1;
        // data loads (8B each), issued before any decode
        uint2 u0 = make_uint2(0u, 0u), u1 = make_uint2(0u, 0u);
        uint2 u2 = make_uint2(0u, 0u), u3 = make_uint2(0u, 0u);
        if (s0 >= 0) u0 = *(const uint2*)(V8 + (size_t)s0 * M + c0);
        if (s1 >= 0) u1 = *(const uint2*)(V8 + (size_t)s1 * M + c0);
        if (s2 >= 0) u2 = *(const uint2*)(V8 + (size_t)s2 * M + c0);
        if (s3 >= 0) u3 = *(const uint2*)(V8 + (size_t)s3 * M + c0);
        acc_fp8x4(acc,     u0.x); acc_fp8x4(acc + 4, u0.y);
        acc_fp8x4(acc,     u1.x); acc_fp8x4(acc + 4, u1.y);
        acc_fp8x4(acc,     u2.x); acc_fp8x4(acc + 4, u2.y);
        acc_fp8x4(acc,     u3.x); acc_fp8x4(acc + 4, u3.y);
    }

    // cross-slot reduction: sum over EPW edge slots
    #pragma unroll
    for (int mask = LPE; mask < 64; mask <<= 1)
        #pragma unroll
        for (int q = 0; q < 8; ++q)
            acc[q] += __shfl_xor(acc[q], mask);

    if (eslot == 0) {
        float inv = inv_deg[dst];
        float r[8];
        #pragma unroll
        for (int q = 0; q < 8; ++q) {
            float v = acc[q] * inv;
            if (bias) v += bias[c0 + q];
            r[q] = v;
        }
        if (Rr) {
            uint4 rr = *(const uint4*)(Rr + (size_t)dst * M + c0);
            uint rw[4] = {rr.x, rr.y, rr.z, rr.w};
            #pragma unroll
            for (int p = 0; p < 4; ++p) {
                r[p * 2 + 0] += bf2f((ushort)(rw[p] & 0xFFFF));
                r[p * 2 + 1] += bf2f((ushort)(rw[p] >> 16));
            }
        }
        #pragma unroll
        for (int q = 0; q < 8; ++q) {
            if constexpr (ACT == 1) r[q] = fmaxf(r[q], 0.f);
            else if constexpr (ACT == 2) r[q] = 1.f / (1.f + expf(-r[q]));
        }
        uint4 o;
        o.x = (uint)f2bf(r[0]) | ((uint)f2bf(r[1]) << 16);
        o.y = (uint)f2bf(r[2]) | ((uint)f2bf(r[3]) << 16);
        o.z = (uint)f2bf(r[4]) | ((uint)f2bf(r[5]) << 16);
        o.w = (uint)f2bf(r[6]) | ((uint)f2bf(r[7]) << 16);
        *(uint4*)(outb + (size_t)dst * ld_out + c0) = o;
        if constexpr (WF8) {
            uint2 o8;
            o8.x = (uint)f2fp8(r[0]) | ((uint)f2fp8(r[1]) << 8) | ((uint)f2fp8(r[2]) << 16) | ((uint)f2fp8(r[3]) << 24);
            o8.y = (uint)f2fp8(r[4]) | ((uint)f2fp8(r[5]) << 8) | ((uint)f2fp8(r[6]) << 16) | ((uint)f2fp8(r[7]) << 24);
            *(uint2*)(out8 + (size_t)dst * M + c0) = o8;
        }
    }
}

// ---------------- heads + cross-entropy (spill-free) ----------------

template<int C>
__device__ inline float ce_from_z(float* z, int label) {
    float m = -1e30f;
    #pragma unroll
    for (int c = 0; c < C; ++c) { z[c] = 1.f / (1.f + expf(-z[c])); m = fmaxf(m, z[c]); }
    float ssum = 0.f, zl = 0.f;
    #pragma unroll
    for (int c = 0; c < C; ++c) { ssum += expf(z[c] - m); if (c == label) zl = z[c]; }
    return (logf(ssum) + m) - zl;
}

__global__ __launch_bounds__(256) void head_ce_k(const ushort* __restrict__ Ah,
                                                 const ushort* __restrict__ hk,
                                                 const float* __restrict__ Wl1, const float* __restrict__ b1, const float* __restrict__ Wr1,
                                                 const float* __restrict__ Wl2, const float* __restrict__ b2, const float* __restrict__ Wr2,
                                                 const float* __restrict__ Wl3, const float* __restrict__ b3, const float* __restrict__ Wr3,
                                                 const int* __restrict__ y,
                                                 float* __restrict__ loss_acc, int n) {
    int nidx = blockIdx.x * blockDim.x + threadIdx.x;
    float lsum = 0.f;
    if (nidx < n) {
        float z0[12], z1[8], z2[5];
        #pragma unroll
        for (int c = 0; c < 12; ++c) z0[c] = b1[c];
        #pragma unroll
        for (int c = 0; c < 8; ++c) z1[c] = b2[c];
        #pragma unroll
        for (int c = 0; c < 5; ++c) z2[c] = b3[c];

        const ushort* ap = Ah + (size_t)nidx * 64;
        const ushort* hp = hk + (size_t)nidx * 64;
        for (int d8 = 0; d8 < 64; d8 += 8) {
            uint4 ua = *(const uint4*)(ap + d8);
            uint4 uh = *(const uint4*)(hp + d8);
            uint aw[4] = {ua.x, ua.y, ua.z, ua.w};
            uint hw[4] = {uh.x, uh.y, uh.z, uh.w};
            #pragma unroll
            for (int p = 0; p < 4; ++p) {
                #pragma unroll
                for (int half = 0; half < 2; ++half) {
                    int d = d8 + p * 2 + half;
                    float av = bf2f((ushort)(half ? (aw[p] >> 16) : (aw[p] & 0xFFFF)));
                    float hv = bf2f((ushort)(half ? (hw[p] >> 16) : (hw[p] & 0xFFFF)));
                    #pragma unroll
                    for (int c = 0; c < 12; ++c)
                        z0[c] = fmaf(av, Wl1[d * 12 + c], fmaf(hv, Wr1[d * 12 + c], z0[c]));
                    #pragma unroll
                    for (int c = 0; c < 8; ++c)
                        z1[c] = fmaf(av, Wl2[d * 8 + c], fmaf(hv, Wr2[d * 8 + c], z1[c]));
                    #pragma unroll
                    for (int c = 0; c < 5; ++c)
                        z2[c] = fmaf(av, Wl3[d * 5 + c], fmaf(hv, Wr3[d * 5 + c], z2[c]));
                }
            }
        }
        lsum  = ce_from_z<12>(z0, y[nidx * 3 + 0]);
        lsum += ce_from_z<8 >(z1, y[nidx * 3 + 1]);
        lsum += ce_from_z<5 >(z2, y[nidx * 3 + 2]);
    }
    for (int off = 32; off > 0; off >>= 1) lsum += __shfl_down(lsum, off);
    __shared__ float ssum[4];
    int wv = threadIdx.x >> 6, ln = threadIdx.x & 63;
    if (ln == 0) ssum[wv] = lsum;
    __syncthreads();
    if (threadIdx.x == 0) atomicAdd(loss_acc, ssum[0] + ssum[1] + ssum[2] + ssum[3]);
}

__global__ void finalize_k(const float* __restrict__ loss_acc, float* __restrict__ out, int n) {
    out[0] = loss_acc[0] * (1.0f / (float)n);
}

// ---------------- host ----------------

extern "C" void kernel_launch(void* const* d_in, const int* in_sizes, int n_in,
                              void* d_out, int out_size, void* d_ws, size_t ws_size,
                              hipStream_t stream) {
    const float* X    = (const float*)d_in[0];
    const int*   esrc = (const int*)d_in[1];
    const int*   edst = (const int*)d_in[2];
    const int*   y    = (const int*)d_in[3];
    const float* Wl_i[2] = {(const float*)d_in[4], (const float*)d_in[7]};
    const float* bl_i[2] = {(const float*)d_in[5], (const float*)d_in[8]};
    const float* Wr_i[2] = {(const float*)d_in[6], (const float*)d_in[9]};
    const float* Wl_m = (const float*)d_in[10], *bl_m = (const float*)d_in[11], *Wr_m = (const float*)d_in[12];
    const float* Wl_o = (const float*)d_in[13], *bl_o = (const float*)d_in[14], *Wr_o = (const float*)d_in[15];
    const float* Wl_t1 = (const float*)d_in[16], *bl_t1 = (const float*)d_in[17], *Wr_t1 = (const float*)d_in[18];
    const float* Wl_t2 = (const float*)d_in[19], *bl_t2 = (const float*)d_in[20], *Wr_t2 = (const float*)d_in[21];
    const float* Wl_t3 = (const float*)d_in[22], *bl_t3 = (const float*)d_in[23], *Wr_t3 = (const float*)d_in[24];

    const int N = NN, E = NE;
    char* p = (char*)d_ws;
    auto alloc = [&](size_t bytes) -> char* {
        char* r = p;
        p += (bytes + 255) & ~(size_t)255;
        return r;
    };
    int*    counts    = (int*)alloc((size_t)N * 4);
    int*    row_start = (int*)alloc((size_t)(N + 1) * 4);
    int*    cursor    = (int*)alloc((size_t)N * 4);
    int*    bsum      = (int*)alloc(64 * 4);
    int*    csr_src   = (int*)alloc((size_t)E * 4);
    float*  inv_deg   = (float*)alloc((size_t)N * 4);
    float*  loss_acc  = (float*)alloc(256);
    uchar*  V8   = (uchar*)alloc((size_t)N * 256);
    ushort* R    = (ushort*)alloc((size_t)N * 256 * 2);
    ushort* xk   = (ushort*)alloc((size_t)N * 256 * 2);
    ushort* hk   = (ushort*)alloc((size_t)N * 64 * 2);
    uchar*  hk8  = (uchar*)alloc((size_t)N * 64);
    ushort* Ah   = (ushort*)alloc((size_t)N * 64 * 2);
    ushort* Wt_i0 = (ushort*)alloc((size_t)256 * 128 * 2);
    ushort* Wt_i1 = (ushort*)alloc((size_t)256 * 128 * 2);
    ushort* Wt_m  = (ushort*)alloc((size_t)512 * 256 * 2);
    ushort* Wt_o  = (ushort*)alloc((size_t)128 * 256 * 2);

    hipMemsetAsync(counts, 0, (size_t)N * 4, stream);
    hipMemsetAsync(loss_acc, 0, 4, stream);
    count_edges_k<<<(E + 255) / 256, 256, 0, stream>>>(edst, counts, E);
    const int NB = (N + 1023) / 1024;
    scan1_k<<<NB, 1024, 0, stream>>>(counts, row_start, bsum, N);
    scan2_k<<<1, 64, 0, stream>>>(bsum, NB);
    scan3_k<<<(N + 255) / 256, 256, 0, stream>>>(counts, bsum, row_start, cursor, inv_deg, N, E);
    fill_csr_k<<<(E + 255) / 256, 256, 0, stream>>>(esrc, edst, cursor, csr_src, E);

    prep_w_k<<<(2 * 128 * 128 + 255) / 256, 256, 0, stream>>>(Wl_i[0], Wr_i[0], Wt_i0, 128, 128);
    prep_w_k<<<(2 * 128 * 128 + 255) / 256, 256, 0, stream>>>(Wl_i[1], Wr_i[1], Wt_i1, 128, 128);
    prep_w_k<<<(2 * 256 * 256 + 255) / 256, 256, 0, stream>>>(Wl_m, Wr_m, Wt_m, 256, 256);
    prep_w_k<<<(2 * 256 * 64 + 255) / 256, 256, 0, stream>>>(Wl_o, Wr_o, Wt_o, 256, 64);

    const int RB = (N + 63) / 64;
    const int AGB = (N + 3) / 4;
    const ushort* Wt_i[2] = {Wt_i0, Wt_i1};

    for (int k = 0; k < 2; ++k) {
        for (int ch = 0; ch < 2; ++ch) {
            const float* Xc = X + (size_t)(k * 2 + ch) * N * 128;
            gemm_mfma_k<true><<<dim3(RB, 2), 256, 0, stream>>>(Xc, 128, Wt_i[ch], V8, R, 128, N);
            agg8_k<128, 1, false><<<AGB, 256, 0, stream>>>(V8, R, bl_i[ch], inv_deg, row_start, csr_src,
                                                           xk + ch * 128, nullptr, 256, N);
        }
        gemm_mfma_k<false><<<dim3(RB, 4), 256, 0, stream>>>(xk, 256, Wt_m, V8, R, 256, N);
        agg8_k<256, 1, false><<<AGB, 256, 0, stream>>>(V8, R, bl_m, inv_deg, row_start, csr_src,
                                                       xk, nullptr, 256, N);
        gemm_mfma_k<false><<<dim3(RB, 1), 256, 0, stream>>>(xk, 256, Wt_o, V8, R, 64, N);
        agg8_k<64, 2, true><<<AGB, 256, 0, stream>>>(V8, R, bl_o, inv_deg, row_start, csr_src,
                                                     hk, hk8, 64, N);
        agg8_k<64, 0, false><<<AGB, 256, 0, stream>>>(hk8, nullptr, nullptr, inv_deg, row_start, csr_src,
                                                      Ah, nullptr, 64, N);
        head_ce_k<<<(N + 255) / 256, 256, 0, stream>>>(Ah, hk,
            Wl_t1 + (size_t)k * 64 * 12, bl_t1 + (size_t)k * 12, Wr_t1 + (size_t)k * 64 * 12,
            Wl_t2 + (size_t)k * 64 * 8,  bl_t2 + (size_t)k * 8,  Wr_t2 + (size_t)k * 64 * 8,
            Wl_t3 + (size_t)k * 64 * 5,  bl_t3 + (size_t)k * 5,  Wr_t3 + (size_t)k * 64 * 5,
            y + (size_t)k * N * 3, loss_acc, N);
    }
    finalize_k<<<1, 1, 0, stream>>>(loss_acc, (float*)d_out, N);
}